// Round 8
// baseline (93.569 us; speedup 1.0000x reference)
//
#include <hip/hip_runtime.h>
#include <math.h>

// Problem shape (fixed by reference setup_inputs):
//   feature_map: (B=8, D=256, H=128, W=128) fp32
//   para_code:   (8, 256)
//   W1 (256,256) b1(256) | Ws (256,256) bs(256) | Wr (256,256) br(256)
//   Wt (256,512) bt(512)
// Output: (8, 256, 128, 128) fp32

#define B_  8
#define D_  256
#define H_  128
#define W_  128
#define PC_ 256
#define PI_F 3.14159f
#define LP_ 129   // padded LDS row stride: 129 % 32 == 1 -> row-step gathers hit
                  // consecutive banks (128 % 32 == 0 was a 32-way conflict for
                  // rotation-dominant planes)
#define NPB 8     // planes per persistent block
#define NBLK (B_ * D_ / NPB)   // 256 blocks = 1 per CU

// ------------- Kernel 1: fused p = relu(para@W1+b1) -> heads ----------------
__global__ void k_params(const float* __restrict__ para,
                         const float* __restrict__ W1, const float* __restrict__ b1,
                         const float* __restrict__ Ws, const float* __restrict__ bs,
                         const float* __restrict__ Wr, const float* __restrict__ br,
                         const float* __restrict__ Wt, const float* __restrict__ bt,
                         float* __restrict__ sc_o, float* __restrict__ c_o,
                         float* __restrict__ s_o,  float* __restrict__ tx_o,
                         float* __restrict__ ty_o) {
    __shared__ float sp[PC_];   // para row
    __shared__ float pp[PC_];   // relu'd hidden
    const int b = blockIdx.x;
    const int which = blockIdx.y;
    const int d = threadIdx.x;
    sp[d] = para[b * PC_ + d];
    __syncthreads();

    float acc = b1[d];
#pragma unroll 8
    for (int k = 0; k < PC_; ++k) {
        acc = fmaf(sp[k], W1[k * PC_ + d], acc);
    }
    pp[d] = fmaxf(acc, 0.0f);
    __syncthreads();

    const int o = b * D_ + d;
    if (which == 0) {
        float as = bs[d];
        float ar = br[d];
#pragma unroll 8
        for (int k = 0; k < PC_; ++k) {
            const float pk = pp[k];
            as = fmaf(pk, Ws[k * PC_ + d], as);
            ar = fmaf(pk, Wr[k * PC_ + d], ar);
        }
        const float scale = 2.0f / (1.0f + expf(-as));      // sigmoid * 2
        const float ang   = tanhf(ar) * PI_F;
        sc_o[o] = scale;
        c_o[o]  = cosf(ang);
        s_o[o]  = sinf(ang);
    } else {
        const float2* __restrict__ Wt2 = (const float2*)Wt;  // (256,256) float2
        float t0 = bt[2 * d];
        float t1 = bt[2 * d + 1];
#pragma unroll 8
        for (int k = 0; k < PC_; ++k) {
            const float pk = pp[k];
            const float2 wt = Wt2[k * PC_ + d];
            t0 = fmaf(pk, wt.x, t0);
            t1 = fmaf(pk, wt.y, t1);
        }
        tx_o[o] = tanhf(t0);
        ty_o[o] = tanhf(t1);
    }
}

// Stage one plane into a padded LDS buffer via global_load_lds DMA.
// chunk c (0..255) = 64 consecutive floats of one half-row; LDS dest is
// wave-uniform base + lane*4 (linear within the chunk, pad untouched).
__device__ __forceinline__
void stage_plane(const float* __restrict__ img, float* __restrict__ dst, int tid) {
    const int wid  = tid >> 6;               // 0..15
    const int lane = tid & 63;
#pragma unroll
    for (int j = 0; j < 16; ++j) {
        const int c    = wid * 16 + j;
        const int row  = c >> 1;
        const int half = c & 1;
        const float* g = img + c * 64 + lane;
        __builtin_amdgcn_global_load_lds(
            (const __attribute__((address_space(1))) unsigned int*)g,
            (__attribute__((address_space(3))) unsigned int*)&dst[row * LP_ + half * 64],
            4, 0, 0);
    }
}

// ------------- Kernel 2: persistent async-double-buffered grid-sample -------
// 256 blocks (1/CU), 1024 threads, 8 planes each, 2x padded LDS buffers
// (130 KiB). Pipeline: issue next plane's global_load_lds DMA (fire-and-
// forget, no VGPR roundtrip, no ds_write phase) -> compute current plane
// with ILP-8 gather batches -> ONE barrier (its vmcnt drain = DMA done).
// launch_bounds(1024,4): 128-VGPR budget so the ILP-8 tap arrays live in
// registers (round 7's (1024,8)=64-VGPR cap made the compiler serialize
// to VGPR=20, exposing full LDS latency per pixel = the flat 84 us).
__global__ __launch_bounds__(1024, 4)
void k_sample(const float* __restrict__ fm,
              const float* __restrict__ sc_a, const float* __restrict__ c_a,
              const float* __restrict__ s_a,  const float* __restrict__ tx_a,
              const float* __restrict__ ty_a,
              float* __restrict__ out) {
    __shared__ float buf[2][LP_ * LP_];          // 2 x 66,564 B = 130 KiB

    const int tid = threadIdx.x;
    const int plane0 = blockIdx.x * NPB;

    // zero pads once (col 128 of rows 0..127, all of row 128): staging never
    // touches them; bilinear taps read them unconditionally with weight 0.
    if (tid < H_)  { buf[0][tid * LP_ + W_] = 0.0f; buf[1][tid * LP_ + W_] = 0.0f; }
    if (tid < LP_) { buf[0][H_ * LP_ + tid] = 0.0f; buf[1][H_ * LP_ + tid] = 0.0f; }

    // prologue: stage plane0 into buf[0]
    stage_plane(fm + (size_t)plane0 * (H_ * W_), buf[0], tid);
    __syncthreads();

    for (int p = 0; p < NPB; ++p) {
        const int cur = p & 1;
        const int plane = plane0 + p;

        // issue next plane's DMA into the alternate buffer; runs under the
        // compute below. Safe: buf[cur^1] was last read before the barrier
        // that ended iteration p-1.
        if (p + 1 < NPB) {
            stage_plane(fm + (size_t)(plane + 1) * (H_ * W_), buf[cur ^ 1], tid);
        }

        const float sc = sc_a[plane];
        const float cc = c_a[plane];
        const float ss = s_a[plane];
        const float tx = tx_a[plane];
        const float ty = ty_a[plane];

        // Fold normalized->pixel mapping: x = w*ax + h*bx + cx:
        const float gstep = 2.0f / (float)(W_ - 1);
        const float k64 = (float)W_ * 0.5f;              // 64
        const float ax =  cc * sc * gstep * k64;
        const float bx = -ss * sc * gstep * k64;
        const float cx = (tx - cc * sc + ss * sc + 1.0f) * k64 - 0.5f;
        const float ay =  ss * sc * gstep * k64;
        const float by =  cc * sc * gstep * k64;
        const float cy = (ty - ss * sc - cc * sc + 1.0f) * k64 - 0.5f;

        // Per-thread base pixel; iteration it adds exactly 8 rows:
        const int h0 = tid >> 7;
        const int w0 = tid & (W_ - 1);
        const float xb = fmaf((float)w0, ax, fmaf((float)h0, bx, cx));
        const float yb = fmaf((float)w0, ay, fmaf((float)h0, by, cy));
        const float dx8 = 8.0f * bx;
        const float dy8 = 8.0f * by;

        const float* __restrict__ lds = buf[cur];
        float* __restrict__ op = out + (size_t)plane * (H_ * W_);

        // ---- 16 px/thread in 2 batches of 8 independent pixels (ILP-8) ----
#pragma unroll
        for (int b8 = 0; b8 < 2; ++b8) {
            float wxv[8], wyv[8];
            float v00[8], v01[8], v10[8], v11[8];
#pragma unroll
            for (int u = 0; u < 8; ++u) {
                const float it = (float)(b8 * 8 + u);
                float x = fmaf(it, dx8, xb);
                float y = fmaf(it, dy8, yb);
                x = fminf(fmaxf(x, 0.0f), (float)(W_ - 1));   // border padding
                y = fminf(fmaxf(y, 0.0f), (float)(H_ - 1));
                const float x0f = floorf(x);
                const float y0f = floorf(y);
                wxv[u] = x - x0f;
                wyv[u] = y - y0f;
                // exact: y0f*129 + x0f <= 16510 < 2^24
                const int base = (int)fmaf(y0f, (float)LP_, x0f);
                v00[u] = lds[base];
                v01[u] = lds[base + 1];           // weight 0 when x at border
                v10[u] = lds[base + LP_];         // weight 0 when y at border
                v11[u] = lds[base + LP_ + 1];
            }
#pragma unroll
            for (int u = 0; u < 8; ++u) {
                const int px = (b8 * 8 + u) * 1024 + tid;
                const float top = v00[u] + wxv[u] * (v01[u] - v00[u]);
                const float bot = v10[u] + wxv[u] * (v11[u] - v10[u]);
                op[px] = top + wyv[u] * (bot - top);
            }
        }

        __syncthreads();   // drains vmcnt (next plane's DMA) + lgkm, then bar
    }
}

extern "C" void kernel_launch(void* const* d_in, const int* in_sizes, int n_in,
                              void* d_out, int out_size, void* d_ws, size_t ws_size,
                              hipStream_t stream) {
    const float* feature_map = (const float*)d_in[0];
    const float* para_code   = (const float*)d_in[1];
    const float* W1 = (const float*)d_in[2];
    const float* b1 = (const float*)d_in[3];
    const float* Ws = (const float*)d_in[4];
    const float* bs = (const float*)d_in[5];
    const float* Wr = (const float*)d_in[6];
    const float* br = (const float*)d_in[7];
    const float* Wt = (const float*)d_in[8];
    const float* bt = (const float*)d_in[9];
    float* out = (float*)d_out;

    // Workspace layout (floats): sc | c | s | tx | ty (each B_*D_)
    float* ws_f = (float*)d_ws;
    float* sc_a  = ws_f;
    float* c_a   = sc_a + B_ * D_;
    float* s_a   = c_a  + B_ * D_;
    float* tx_a  = s_a  + B_ * D_;
    float* ty_a  = tx_a + B_ * D_;

    k_params<<<dim3(B_, 2), PC_, 0, stream>>>(para_code, W1, b1, Ws, bs, Wr, br,
                                              Wt, bt, sc_a, c_a, s_a, tx_a, ty_a);
    k_sample<<<NBLK, 1024, 0, stream>>>(feature_map, sc_a, c_a, s_a, tx_a, ty_a, out);
}

// Round 9
// 81.699 us; speedup vs baseline: 1.1453x; 1.1453x over previous
//
#include <hip/hip_runtime.h>
#include <math.h>

// Problem shape (fixed by reference setup_inputs):
//   feature_map: (B=8, D=256, H=128, W=128) fp32
//   para_code:   (8, 256)
//   W1 (256,256) b1(256) | Ws (256,256) bs(256) | Wr (256,256) br(256)
//   Wt (256,512) bt(512)
// Output: (8, 256, 128, 128) fp32

#define B_  8
#define D_  256
#define H_  128
#define W_  128
#define PC_ 256
#define PI_F 3.14159f
#define LP_ 129   // padded LDS row stride: 129 % 32 == 1 -> row-step gathers hit
                  // consecutive banks (128 % 32 == 0 was a 32-way conflict for
                  // rotation-dominant planes)

// ------------- Kernel 1: fused p = relu(para@W1+b1) -> heads ----------------
__global__ void k_params(const float* __restrict__ para,
                         const float* __restrict__ W1, const float* __restrict__ b1,
                         const float* __restrict__ Ws, const float* __restrict__ bs,
                         const float* __restrict__ Wr, const float* __restrict__ br,
                         const float* __restrict__ Wt, const float* __restrict__ bt,
                         float* __restrict__ sc_o, float* __restrict__ c_o,
                         float* __restrict__ s_o,  float* __restrict__ tx_o,
                         float* __restrict__ ty_o) {
    __shared__ float sp[PC_];   // para row
    __shared__ float pp[PC_];   // relu'd hidden
    const int b = blockIdx.x;
    const int which = blockIdx.y;
    const int d = threadIdx.x;
    sp[d] = para[b * PC_ + d];
    __syncthreads();

    float acc = b1[d];
#pragma unroll 8
    for (int k = 0; k < PC_; ++k) {
        acc = fmaf(sp[k], W1[k * PC_ + d], acc);
    }
    pp[d] = fmaxf(acc, 0.0f);
    __syncthreads();

    const int o = b * D_ + d;
    if (which == 0) {
        float as = bs[d];
        float ar = br[d];
#pragma unroll 8
        for (int k = 0; k < PC_; ++k) {
            const float pk = pp[k];
            as = fmaf(pk, Ws[k * PC_ + d], as);
            ar = fmaf(pk, Wr[k * PC_ + d], ar);
        }
        const float scale = 2.0f / (1.0f + expf(-as));      // sigmoid * 2
        const float ang   = tanhf(ar) * PI_F;
        sc_o[o] = scale;
        c_o[o]  = cosf(ang);
        s_o[o]  = sinf(ang);
    } else {
        const float2* __restrict__ Wt2 = (const float2*)Wt;  // (256,256) float2
        float t0 = bt[2 * d];
        float t1 = bt[2 * d + 1];
#pragma unroll 8
        for (int k = 0; k < PC_; ++k) {
            const float pk = pp[k];
            const float2 wt = Wt2[k * PC_ + d];
            t0 = fmaf(pk, wt.x, t0);
            t1 = fmaf(pk, wt.y, t1);
        }
        tx_o[o] = tanhf(t0);
        ty_o[o] = tanhf(t1);
    }
}

// ------------- Kernel 2: affine grid-sample via padded LDS plane ------------
// 2048 blocks x 512 threads, one plane each, 2 blocks/CU (16 waves/CU — same
// TLP as every ~84us round). The ONE thing changed this round: register
// budget. launch_bounds(512,1) = 512-VGPR budget; rounds 3-8 the allocator
// kept choosing 20-64 VGPR schedules that re-serialized the gather chain
// (addr -> ds_read2 -> lgkmcnt(0) -> lerp, ~280cy/px observed). ILP-16
// batches: 16 addresses, 32 ds_read2 issued back-to-back (counted-lgkmcnt
// drain = throughput-bound), 16 lerp+stores. ~120 live VGPRs.
__global__ __launch_bounds__(512, 1)
void k_sample(const float* __restrict__ fm,
              const float* __restrict__ sc_a, const float* __restrict__ c_a,
              const float* __restrict__ s_a,  const float* __restrict__ tx_a,
              const float* __restrict__ ty_a,
              float* __restrict__ out) {
    __shared__ float buf[LP_ * LP_];             // 129 x 129 floats, ~65 KiB

    const int plane = blockIdx.x;                // 0 .. B_*D_-1
    const float* __restrict__ img = fm + (size_t)plane * (H_ * W_);
    float* __restrict__ op = out + (size_t)plane * (H_ * W_);
    const int tid = threadIdx.x;

    // ---- stage plane -> padded LDS via global_load_lds (size=4) ----
    // chunk c (0..255) = 64 consecutive floats of one half-row; LDS dest is
    // wave-uniform base + lane*4 (linear within the chunk, pad untouched).
    {
        const int wid  = tid >> 6;               // 0..7
        const int lane = tid & 63;
#pragma unroll
        for (int j = 0; j < 32; ++j) {
            const int c    = wid * 32 + j;
            const int row  = c >> 1;
            const int half = c & 1;
            const float* g = img + c * 64 + lane;
            __builtin_amdgcn_global_load_lds(
                (const __attribute__((address_space(1))) unsigned int*)g,
                (__attribute__((address_space(3))) unsigned int*)&buf[row * LP_ + half * 64],
                4, 0, 0);
        }
    }
    // zero pads: column 128 of rows 0..127, all 129 entries of row 128 —
    // bilinear taps read them unconditionally with weight exactly 0.
    if (tid < H_)  buf[tid * LP_ + W_] = 0.0f;
    if (tid < LP_) buf[H_ * LP_ + tid] = 0.0f;

    const float sc = sc_a[plane];
    const float cc = c_a[plane];
    const float ss = s_a[plane];
    const float tx = tx_a[plane];
    const float ty = ty_a[plane];

    // Fold normalized->pixel mapping: x = w*ax + h*bx + cx (align_corners=F):
    const float gstep = 2.0f / (float)(W_ - 1);
    const float k64 = (float)W_ * 0.5f;                  // 64
    const float ax =  cc * sc * gstep * k64;
    const float bx = -ss * sc * gstep * k64;
    const float cx = (tx - cc * sc + ss * sc + 1.0f) * k64 - 0.5f;
    const float ay =  ss * sc * gstep * k64;
    const float by =  cc * sc * gstep * k64;
    const float cy = (ty - ss * sc - cc * sc + 1.0f) * k64 - 0.5f;

    // Per-thread base pixel (h0 = tid>>7, w0 = tid&127); iteration it adds
    // exactly 4 rows (512 threads / 128 cols): x_it = xb + it*dx4.
    const int h0 = tid >> 7;
    const int w0 = tid & (W_ - 1);
    const float xb = fmaf((float)w0, ax, fmaf((float)h0, bx, cx));
    const float yb = fmaf((float)w0, ay, fmaf((float)h0, by, cy));
    const float dx4 = 4.0f * bx;
    const float dy4 = 4.0f * by;

    __syncthreads();   // drains the global_load_lds vmcnt traffic

    // ---- 32 px/thread in 2 batches of 16 independent pixels (ILP-16) ----
#pragma unroll
    for (int b16 = 0; b16 < 2; ++b16) {
        float wxv[16], wyv[16];
        float v00[16], v01[16], v10[16], v11[16];
#pragma unroll
        for (int u = 0; u < 16; ++u) {
            const float it = (float)(b16 * 16 + u);
            float x = fmaf(it, dx4, xb);
            float y = fmaf(it, dy4, yb);
            x = fminf(fmaxf(x, 0.0f), (float)(W_ - 1));   // border padding
            y = fminf(fmaxf(y, 0.0f), (float)(H_ - 1));
            const float x0f = floorf(x);
            const float y0f = floorf(y);
            wxv[u] = x - x0f;
            wyv[u] = y - y0f;
            // exact: y0f*129 + x0f <= 16510 < 2^24
            const int base = (int)fmaf(y0f, (float)LP_, x0f);
            v00[u] = buf[base];
            v01[u] = buf[base + 1];           // weight 0 when x at border
            v10[u] = buf[base + LP_];         // weight 0 when y at border
            v11[u] = buf[base + LP_ + 1];
        }
#pragma unroll
        for (int u = 0; u < 16; ++u) {
            const int px = (b16 * 16 + u) * 512 + tid;
            const float top = v00[u] + wxv[u] * (v01[u] - v00[u]);
            const float bot = v10[u] + wxv[u] * (v11[u] - v10[u]);
            op[px] = top + wyv[u] * (bot - top);
        }
    }
}

extern "C" void kernel_launch(void* const* d_in, const int* in_sizes, int n_in,
                              void* d_out, int out_size, void* d_ws, size_t ws_size,
                              hipStream_t stream) {
    const float* feature_map = (const float*)d_in[0];
    const float* para_code   = (const float*)d_in[1];
    const float* W1 = (const float*)d_in[2];
    const float* b1 = (const float*)d_in[3];
    const float* Ws = (const float*)d_in[4];
    const float* bs = (const float*)d_in[5];
    const float* Wr = (const float*)d_in[6];
    const float* br = (const float*)d_in[7];
    const float* Wt = (const float*)d_in[8];
    const float* bt = (const float*)d_in[9];
    float* out = (float*)d_out;

    // Workspace layout (floats): sc | c | s | tx | ty (each B_*D_)
    float* ws_f = (float*)d_ws;
    float* sc_a  = ws_f;
    float* c_a   = sc_a + B_ * D_;
    float* s_a   = c_a  + B_ * D_;
    float* tx_a  = s_a  + B_ * D_;
    float* ty_a  = tx_a + B_ * D_;

    k_params<<<dim3(B_, 2), PC_, 0, stream>>>(para_code, W1, b1, Ws, bs, Wr, br,
                                              Wt, bt, sc_a, c_a, s_a, tx_a, ty_a);
    k_sample<<<B_ * D_, 512, 0, stream>>>(feature_map, sc_a, c_a, s_a, tx_a, ty_a, out);
}